// Round 6
// baseline (355.772 us; speedup 1.0000x reference)
//
#include <hip/hip_runtime.h>

// QNet forward, MI355X. Round 6: round-5 occupancy/coalescing pass + fix of
// the Mn-init regression (grid-stride loop, not if(t<1024) with 512 threads).
// enc: 64-row blocks, 17.4KB LDS -> 8 blocks/CU; coalesced obs staging;
//      LDS-transpose epilogue for dwordx4 h stores.
// dec: 8-row blocks, 73.9KB LDS -> 2 blocks/CU; duplicated-row m-tiles;
//      fast tanh. Packs fused into one kernel.
// B=8192, A=32, NOBS=128, NH1=128, HX=64, NACT=16. fp32 in/out.

#define NB   8192
#define NA   32
#define NOBS 128
#define NH1  128
#define HXX  64
#define NACT 16

typedef _Float16 half8 __attribute__((ext_vector_type(8)));
typedef _Float16 half4 __attribute__((ext_vector_type(4)));
typedef float    floatx4 __attribute__((ext_vector_type(4)));

#define MFMA16(af, bf, c) __builtin_amdgcn_mfma_f32_16x16x32_f16((af), (bf), (c), 0, 0, 0)

// ws offsets in halfs
#define HWS_OFF 0
#define W1P_OFF (NB * NA * HXX)                    // 16,777,216
#define W1P_CNT (NA * 8 * 4 * 512)                 // 524,288
#define W2P_OFF (W1P_OFF + W1P_CNT)
#define W2P_CNT (NA * 4 * 4 * 512)                 // 262,144
#define WCP_OFF (W2P_OFF + W2P_CNT)
#define WCP_CNT (NA * 4 * 4 * 512)                 // 262,144
#define WDP_OFF (WCP_OFF + WCP_CNT)
#define WDP_CNT (NA * 1 * 2 * 512)                 // 32,768
#define PACK_TOTAL (W1P_CNT + W2P_CNT + WCP_CNT + WDP_CNT)   // 1,081,344

#define DEC_LDS (256 * 136 * 2 + 32 * 32 * 4 + 128)          // 73,856 B

__device__ __forceinline__ float fast_tanh(float x) {
    x = fminf(fmaxf(x, -10.f), 10.f);
    float e2 = __expf(2.f * x);
    return (e2 - 1.f) / (e2 + 1.f);
}

// ---------------------------------------------------------------------------
// Unified pack: fp32 weights -> f16 MFMA B-fragments for W1/W2/Wc/Wd.
// frag(a,nt,s)[l*8+j] = W[a][s*32+(l>>4)*8+j][nt*16+(l&15)]
// ---------------------------------------------------------------------------
extern "C" __global__ void pack_kernel(const float* __restrict__ W1,
                                       const float* __restrict__ W2,
                                       const float* __restrict__ Wc,
                                       const float* __restrict__ Wd,
                                       _Float16* __restrict__ ws)
{
    int e = blockIdx.x * 256 + threadIdx.x;
    if (e >= PACK_TOTAL) return;
    const float* src; _Float16* dst; int K, N, NT, NS, r;
    if (e < W1P_CNT) {
        src = W1; dst = ws + W1P_OFF; K = 128; N = 128; NT = 8; NS = 4; r = e;
    } else if (e < W1P_CNT + W2P_CNT) {
        src = W2; dst = ws + W2P_OFF; K = 128; N = 64; NT = 4; NS = 4; r = e - W1P_CNT;
    } else if (e < W1P_CNT + W2P_CNT + WCP_CNT) {
        src = Wc; dst = ws + WCP_OFF; K = 128; N = 64; NT = 4; NS = 4; r = e - W1P_CNT - W2P_CNT;
    } else {
        src = Wd; dst = ws + WDP_OFF; K = 64; N = 16; NT = 1; NS = 2; r = e - W1P_CNT - W2P_CNT - WCP_CNT;
    }
    int j = r & 7, l = (r >> 3) & 63;
    int rest = r >> 9;
    int s  = rest % NS; rest /= NS;
    int nt = rest % NT; rest /= NT;
    int a  = rest;
    int k = s * 32 + (l >> 4) * 8 + j;
    int n = nt * 16 + (l & 15);
    dst[r] = (_Float16)src[((size_t)a * K + k) * N + n];
}

// ---------------------------------------------------------------------------
// Encoder: h = relu(relu(obs@W1+b1)@W2+b2) -> ws (f16, [b][a][c])
// grid (128, 32), block 256 (4 waves). 64 rows/block, wave w owns rows
// 16w..16w+15 (one m-tile). LDS 17.4KB -> 8 blocks/CU.
// ---------------------------------------------------------------------------
extern "C" __global__ __launch_bounds__(256, 8)
void enc_kernel(const float* __restrict__ obs,
                const float* __restrict__ b1,
                const float* __restrict__ b2,
                const _Float16* __restrict__ W1p,
                const _Float16* __restrict__ W2p,
                _Float16* __restrict__ hws)
{
    __shared__ _Float16 A[64 * 136];   // 17,408 B

    const int t  = threadIdx.x;
    const int a  = blockIdx.y;
    const int b0 = blockIdx.x * 64;

    {   // stage obs fp32 -> f16: 8 lanes/row, 128B contiguous chunks per row
        const int j = t & 7;
        #pragma unroll
        for (int p = 0; p < 2; ++p) {
            const int row = (t >> 3) + 32 * p;
            const float4* src = (const float4*)(obs + ((size_t)(b0 + row) * NA + a) * NOBS);
            _Float16* dst = A + row * 136;
            #pragma unroll
            for (int q = 0; q < 4; ++q) {
                float4 g = src[j + 8 * q];
                half4 hv; hv[0] = (_Float16)g.x; hv[1] = (_Float16)g.y;
                hv[2] = (_Float16)g.z; hv[3] = (_Float16)g.w;
                *(half4*)&dst[(j + 8 * q) * 4] = hv;
            }
        }
    }
    const int w = t >> 6, l = t & 63, lm = l & 15, lq = l >> 4;

    float b1v[8], b2v[4];
    #pragma unroll
    for (int nt = 0; nt < 8; ++nt) b1v[nt] = b1[a * NH1 + nt * 16 + lm];
    #pragma unroll
    for (int nt = 0; nt < 4; ++nt) b2v[nt] = b2[a * HXX + nt * 16 + lm];

    __syncthreads();
    // From here each wave touches only its own rows 16w..16w+15: no barriers.

    // ---- GEMM1: x = obs @ W1  (8 n-tiles, K=128)
    floatx4 acc[8];
    #pragma unroll
    for (int nt = 0; nt < 8; ++nt) acc[nt] = (floatx4){0.f, 0.f, 0.f, 0.f};
    for (int s = 0; s < 4; ++s) {
        half8 af = *(const half8*)&A[(w * 16 + lm) * 136 + s * 32 + lq * 8];
        #pragma unroll
        for (int nt = 0; nt < 8; ++nt) {
            half8 bf = *(const half8*)&W1p[(((a * 8 + nt) * 4 + s) * 512) + l * 8];
            acc[nt] = MFMA16(af, bf, acc[nt]);
        }
    }
    // relu + X back into own rows
    #pragma unroll
    for (int nt = 0; nt < 8; ++nt)
        #pragma unroll
        for (int v = 0; v < 4; ++v) {
            float x = fmaxf(acc[nt][v] + b1v[nt], 0.f);
            A[(w * 16 + lq * 4 + v) * 136 + nt * 16 + lm] = (_Float16)x;
        }

    // ---- GEMM2: h = X @ W2  (4 n-tiles)
    floatx4 acc2[4];
    #pragma unroll
    for (int nt = 0; nt < 4; ++nt) acc2[nt] = (floatx4){0.f, 0.f, 0.f, 0.f};
    for (int s = 0; s < 4; ++s) {
        half8 af = *(const half8*)&A[(w * 16 + lm) * 136 + s * 32 + lq * 8];
        #pragma unroll
        for (int nt = 0; nt < 4; ++nt) {
            half8 bf = *(const half8*)&W2p[(((a * 4 + nt) * 4 + s) * 512) + l * 8];
            acc2[nt] = MFMA16(af, bf, acc2[nt]);
        }
    }
    // relu -> f16 into own rows (cols 0..63), then coalesced dwordx4 stores
    #pragma unroll
    for (int nt = 0; nt < 4; ++nt)
        #pragma unroll
        for (int v = 0; v < 4; ++v) {
            float x = fmaxf(acc2[nt][v] + b2v[nt], 0.f);
            A[(w * 16 + lq * 4 + v) * 136 + nt * 16 + lm] = (_Float16)x;
        }
    {
        const int rr = l >> 2, cc = l & 3;
        #pragma unroll
        for (int hh = 0; hh < 2; ++hh) {
            const int chunk = cc + 4 * hh;
            half8 hv = *(const half8*)&A[(w * 16 + rr) * 136 + chunk * 8];
            *(half8*)&hws[((size_t)(b0 + w * 16 + rr) * NA + a) * HXX + chunk * 8] = hv;
        }
    }
}

// ---------------------------------------------------------------------------
// Decoder: comm masked-mean + tanh([h|comm]@Wc+bc) @ Wd + bd.
// grid 1024, block 512 (8 waves). Block = 8 batch rows x 32 agents.
// H (LDS): row index = agent*8 + r, 136-half stride; cols 0..63 h, 64..127 comm.
// Wave w owns agents 4w..4w+3. m-tiles use duplicated rows (lm>=8 -> lm-8),
// stores predicated to valid rows.
// ---------------------------------------------------------------------------
extern "C" __global__ __launch_bounds__(512, 4)
void dec_kernel(const _Float16* __restrict__ hws,
                const int* __restrict__ cmask,
                const float* __restrict__ bc,
                const float* __restrict__ bd,
                const _Float16* __restrict__ Wcp,
                const _Float16* __restrict__ Wdp,
                float* __restrict__ out)
{
    extern __shared__ char smem[];
    _Float16* H  = (_Float16*)smem;                  // 256 x 136
    float*    Mn = (float*)(smem + 256 * 136 * 2);   // 32 x 32
    int*      cnt = (int*)(Mn + 1024);               // 32

    const int t  = threadIdx.x;
    const int b0 = blockIdx.x * 8;

    {   // stage h tile: 8 rows x 32 agents x 64 = 2048 uint4, fully coalesced
        const uint4* src = (const uint4*)(hws + (size_t)b0 * NA * HXX);
        #pragma unroll
        for (int it = 0; it < 4; ++it) {
            int idx = it * 512 + t;
            int r = idx >> 8, rem = idx & 255, ai = rem >> 3, c8 = rem & 7;
            *(uint4*)&H[(ai * 8 + r) * 136 + c8 * 8] = src[idx];
        }
    }
    if (t < NA) {
        int c = 0;
        for (int j = 0; j < NA; ++j) c += (j != t && cmask[t * NA + j]) ? 1 : 0;
        cnt[t] = c;
    }
    __syncthreads();

    // normalized mask — grid-stride: 512 threads cover all 1024 entries
    // (round-5 bug: if(t<1024) left rows 16..31 uninitialized)
    for (int e = t; e < NA * NA; e += 512) {
        int i = e >> 5, j = e & 31;
        float v = 0.f;
        if (j != i && cmask[i * NA + j]) {
            int c = cnt[i]; v = 1.0f / (float)(c > 1 ? c : 1);
        }
        Mn[e] = v;
    }
    __syncthreads();

    {   // comm: wave w -> row r=w; lane cw handles one channel, all agents
        const int r = t >> 6, cw = t & 63;
        float hj[NA];
        #pragma unroll
        for (int j = 0; j < NA; ++j) hj[j] = (float)H[(j * 8 + r) * 136 + cw];
        for (int i = 0; i < NA; ++i) {
            float acc = 0.f;
            #pragma unroll
            for (int j = 0; j < NA; ++j) acc += Mn[i * 32 + j] * hj[j];
            H[(i * 8 + r) * 136 + 64 + cw] = (_Float16)acc;
        }
    }
    __syncthreads();

    const int w = t >> 6, l = t & 63, lm = l & 15, lq = l >> 4;
    const int rdup = lm & 7;   // rows duplicated for lm>=8

    // ---- Wc GEMM: per wave 4 agents x 4 n-tiles x K=128
    floatx4 acc[4][4];
    #pragma unroll
    for (int g = 0; g < 4; ++g)
        #pragma unroll
        for (int nt = 0; nt < 4; ++nt) acc[g][nt] = (floatx4){0.f, 0.f, 0.f, 0.f};

    for (int s = 0; s < 4; ++s) {
        #pragma unroll
        for (int g = 0; g < 4; ++g) {
            int ag = w * 4 + g;
            half8 af = *(const half8*)&H[(ag * 8 + rdup) * 136 + s * 32 + lq * 8];
            #pragma unroll
            for (int nt = 0; nt < 4; ++nt) {
                half8 bf = *(const half8*)&Wcp[(((ag * 4 + nt) * 4 + s) * 512) + l * 8];
                acc[g][nt] = MFMA16(af, bf, acc[g][nt]);
            }
        }
    }

    // tanh -> h2 (f16) into own agents' rows, cols 0..63 (valid rows only)
    #pragma unroll
    for (int g = 0; g < 4; ++g) {
        int ag = w * 4 + g;
        #pragma unroll
        for (int nt = 0; nt < 4; ++nt) {
            float bcv = bc[ag * HXX + nt * 16 + lm];
            if (lq < 2) {
                #pragma unroll
                for (int v = 0; v < 4; ++v) {
                    int m = lq * 4 + v;
                    float x = fast_tanh(acc[g][nt][v] + bcv);
                    H[(ag * 8 + m) * 136 + nt * 16 + lm] = (_Float16)x;
                }
            }
        }
    }
    // own-wave rows only -> no barrier (wave-internal LDS RAW)

    // ---- Wd GEMM: K=64, N=16
    floatx4 acc3[4];
    #pragma unroll
    for (int g = 0; g < 4; ++g) acc3[g] = (floatx4){0.f, 0.f, 0.f, 0.f};
    for (int s = 0; s < 2; ++s) {
        #pragma unroll
        for (int g = 0; g < 4; ++g) {
            int ag = w * 4 + g;
            half8 af = *(const half8*)&H[(ag * 8 + rdup) * 136 + s * 32 + lq * 8];
            half8 bf = *(const half8*)&Wdp[((ag * 2 + s) * 512) + l * 8];
            acc3[g] = MFMA16(af, bf, acc3[g]);
        }
    }

    #pragma unroll
    for (int g = 0; g < 4; ++g) {
        int ag = w * 4 + g;
        float bdv = bd[ag * NACT + lm];
        if (lq < 2) {
            #pragma unroll
            for (int v = 0; v < 4; ++v) {
                int m = lq * 4 + v;
                out[((size_t)(b0 + m) * NA + ag) * NACT + lm] = acc3[g][v] + bdv;
            }
        }
    }
}

// ---------------------------------------------------------------------------
extern "C" void kernel_launch(void* const* d_in, const int* in_sizes, int n_in,
                              void* d_out, int out_size, void* d_ws, size_t ws_size,
                              hipStream_t stream)
{
    const float* obs = (const float*)d_in[0];
    const float* W1  = (const float*)d_in[1];
    const float* b1  = (const float*)d_in[2];
    const float* W2  = (const float*)d_in[3];
    const float* b2  = (const float*)d_in[4];
    const float* Wc  = (const float*)d_in[7];
    const float* bc  = (const float*)d_in[8];
    const float* Wd  = (const float*)d_in[9];
    const float* bd  = (const float*)d_in[10];
    const int*   cm  = (const int*)d_in[11];

    float*    outp = (float*)d_out;
    _Float16* ws   = (_Float16*)d_ws;

    _Float16* hws = ws + HWS_OFF;
    _Float16* W1p = ws + W1P_OFF;
    _Float16* W2p = ws + W2P_OFF;
    _Float16* Wcp = ws + WCP_OFF;
    _Float16* Wdp = ws + WDP_OFF;

    hipLaunchKernelGGL(pack_kernel, dim3((PACK_TOTAL + 255) / 256), dim3(256), 0, stream,
                       W1, W2, Wc, Wd, ws);

    hipLaunchKernelGGL(enc_kernel, dim3(NB / 64, NA), dim3(256), 0, stream,
                       obs, b1, b2, W1p, W2p, hws);

    (void)hipFuncSetAttribute((const void*)dec_kernel,
                              hipFuncAttributeMaxDynamicSharedMemorySize, DEC_LDS);
    hipLaunchKernelGGL(dec_kernel, dim3(NB / 8), dim3(512), DEC_LDS, stream,
                       hws, cm, bc, bd, Wcp, Wdp, outp);
}

// Round 7
// 345.129 us; speedup vs baseline: 1.0308x; 1.0308x over previous
//
#include <hip/hip_runtime.h>

// QNet forward, MI355X. Round 7: fix r6's scratch-spill regression.
// r6's __launch_bounds__(256,8) capped VGPRs at 64 -> ~92B/thread spill
// (WRITE_SIZE 126MB vs 34MB ideal). enc now unbounded min-waves; dec (512,2).
// enc: 64-row blocks, 17.4KB LDS; coalesced obs staging; transpose epilogue.
// dec: 8-row blocks, 73.9KB LDS -> 2 blocks/CU; dup-row m-tiles; fast tanh.
// B=8192, A=32, NOBS=128, NH1=128, HX=64, NACT=16. fp32 in/out.

#define NB   8192
#define NA   32
#define NOBS 128
#define NH1  128
#define HXX  64
#define NACT 16

typedef _Float16 half8 __attribute__((ext_vector_type(8)));
typedef _Float16 half4 __attribute__((ext_vector_type(4)));
typedef float    floatx4 __attribute__((ext_vector_type(4)));

#define MFMA16(af, bf, c) __builtin_amdgcn_mfma_f32_16x16x32_f16((af), (bf), (c), 0, 0, 0)

// ws offsets in halfs
#define HWS_OFF 0
#define W1P_OFF (NB * NA * HXX)                    // 16,777,216
#define W1P_CNT (NA * 8 * 4 * 512)                 // 524,288
#define W2P_OFF (W1P_OFF + W1P_CNT)
#define W2P_CNT (NA * 4 * 4 * 512)                 // 262,144
#define WCP_OFF (W2P_OFF + W2P_CNT)
#define WCP_CNT (NA * 4 * 4 * 512)                 // 262,144
#define WDP_OFF (WCP_OFF + WCP_CNT)
#define WDP_CNT (NA * 1 * 2 * 512)                 // 32,768
#define PACK_TOTAL (W1P_CNT + W2P_CNT + WCP_CNT + WDP_CNT)   // 1,081,344

#define DEC_LDS (256 * 136 * 2 + 32 * 32 * 4 + 128)          // 73,856 B

__device__ __forceinline__ float fast_tanh(float x) {
    x = fminf(fmaxf(x, -10.f), 10.f);
    float e2 = __expf(2.f * x);
    return (e2 - 1.f) / (e2 + 1.f);
}

// ---------------------------------------------------------------------------
// Unified pack: fp32 weights -> f16 MFMA B-fragments for W1/W2/Wc/Wd.
// frag(a,nt,s)[l*8+j] = W[a][s*32+(l>>4)*8+j][nt*16+(l&15)]
// ---------------------------------------------------------------------------
extern "C" __global__ void pack_kernel(const float* __restrict__ W1,
                                       const float* __restrict__ W2,
                                       const float* __restrict__ Wc,
                                       const float* __restrict__ Wd,
                                       _Float16* __restrict__ ws)
{
    int e = blockIdx.x * 256 + threadIdx.x;
    if (e >= PACK_TOTAL) return;
    const float* src; _Float16* dst; int K, N, NT, NS, r;
    if (e < W1P_CNT) {
        src = W1; dst = ws + W1P_OFF; K = 128; N = 128; NT = 8; NS = 4; r = e;
    } else if (e < W1P_CNT + W2P_CNT) {
        src = W2; dst = ws + W2P_OFF; K = 128; N = 64; NT = 4; NS = 4; r = e - W1P_CNT;
    } else if (e < W1P_CNT + W2P_CNT + WCP_CNT) {
        src = Wc; dst = ws + WCP_OFF; K = 128; N = 64; NT = 4; NS = 4; r = e - W1P_CNT - W2P_CNT;
    } else {
        src = Wd; dst = ws + WDP_OFF; K = 64; N = 16; NT = 1; NS = 2; r = e - W1P_CNT - W2P_CNT - WCP_CNT;
    }
    int j = r & 7, l = (r >> 3) & 63;
    int rest = r >> 9;
    int s  = rest % NS; rest /= NS;
    int nt = rest % NT; rest /= NT;
    int a  = rest;
    int k = s * 32 + (l >> 4) * 8 + j;
    int n = nt * 16 + (l & 15);
    dst[r] = (_Float16)src[((size_t)a * K + k) * N + n];
}

// ---------------------------------------------------------------------------
// Encoder: h = relu(relu(obs@W1+b1)@W2+b2) -> ws (f16, [b][a][c])
// grid (128, 32), block 256 (4 waves). 64 rows/block, wave w owns rows
// 16w..16w+15 (one m-tile). No min-wave bound: VGPR-free, no spill.
// ---------------------------------------------------------------------------
extern "C" __global__ __launch_bounds__(256)
void enc_kernel(const float* __restrict__ obs,
                const float* __restrict__ b1,
                const float* __restrict__ b2,
                const _Float16* __restrict__ W1p,
                const _Float16* __restrict__ W2p,
                _Float16* __restrict__ hws)
{
    __shared__ _Float16 A[64 * 136];   // 17,408 B

    const int t  = threadIdx.x;
    const int a  = blockIdx.y;
    const int b0 = blockIdx.x * 64;

    {   // stage obs fp32 -> f16: 8 lanes/row, 128B contiguous chunks per row
        const int j = t & 7;
        #pragma unroll
        for (int p = 0; p < 2; ++p) {
            const int row = (t >> 3) + 32 * p;
            const float4* src = (const float4*)(obs + ((size_t)(b0 + row) * NA + a) * NOBS);
            _Float16* dst = A + row * 136;
            #pragma unroll
            for (int q = 0; q < 4; ++q) {
                float4 g = src[j + 8 * q];
                half4 hv; hv[0] = (_Float16)g.x; hv[1] = (_Float16)g.y;
                hv[2] = (_Float16)g.z; hv[3] = (_Float16)g.w;
                *(half4*)&dst[(j + 8 * q) * 4] = hv;
            }
        }
    }
    const int w = t >> 6, l = t & 63, lm = l & 15, lq = l >> 4;

    float b1v[8], b2v[4];
    #pragma unroll
    for (int nt = 0; nt < 8; ++nt) b1v[nt] = b1[a * NH1 + nt * 16 + lm];
    #pragma unroll
    for (int nt = 0; nt < 4; ++nt) b2v[nt] = b2[a * HXX + nt * 16 + lm];

    __syncthreads();
    // From here each wave touches only its own rows 16w..16w+15: no barriers.

    // ---- GEMM1: x = obs @ W1  (8 n-tiles, K=128)
    floatx4 acc[8];
    #pragma unroll
    for (int nt = 0; nt < 8; ++nt) acc[nt] = (floatx4){0.f, 0.f, 0.f, 0.f};
    for (int s = 0; s < 4; ++s) {
        half8 af = *(const half8*)&A[(w * 16 + lm) * 136 + s * 32 + lq * 8];
        #pragma unroll
        for (int nt = 0; nt < 8; ++nt) {
            half8 bf = *(const half8*)&W1p[(((a * 8 + nt) * 4 + s) * 512) + l * 8];
            acc[nt] = MFMA16(af, bf, acc[nt]);
        }
    }
    // relu + X back into own rows
    #pragma unroll
    for (int nt = 0; nt < 8; ++nt)
        #pragma unroll
        for (int v = 0; v < 4; ++v) {
            float x = fmaxf(acc[nt][v] + b1v[nt], 0.f);
            A[(w * 16 + lq * 4 + v) * 136 + nt * 16 + lm] = (_Float16)x;
        }

    // ---- GEMM2: h = X @ W2  (4 n-tiles)
    floatx4 acc2[4];
    #pragma unroll
    for (int nt = 0; nt < 4; ++nt) acc2[nt] = (floatx4){0.f, 0.f, 0.f, 0.f};
    for (int s = 0; s < 4; ++s) {
        half8 af = *(const half8*)&A[(w * 16 + lm) * 136 + s * 32 + lq * 8];
        #pragma unroll
        for (int nt = 0; nt < 4; ++nt) {
            half8 bf = *(const half8*)&W2p[(((a * 4 + nt) * 4 + s) * 512) + l * 8];
            acc2[nt] = MFMA16(af, bf, acc2[nt]);
        }
    }
    // relu -> f16 into own rows (cols 0..63), then coalesced dwordx4 stores
    #pragma unroll
    for (int nt = 0; nt < 4; ++nt)
        #pragma unroll
        for (int v = 0; v < 4; ++v) {
            float x = fmaxf(acc2[nt][v] + b2v[nt], 0.f);
            A[(w * 16 + lq * 4 + v) * 136 + nt * 16 + lm] = (_Float16)x;
        }
    {
        const int rr = l >> 2, cc = l & 3;
        #pragma unroll
        for (int hh = 0; hh < 2; ++hh) {
            const int chunk = cc + 4 * hh;
            half8 hv = *(const half8*)&A[(w * 16 + rr) * 136 + chunk * 8];
            *(half8*)&hws[((size_t)(b0 + w * 16 + rr) * NA + a) * HXX + chunk * 8] = hv;
        }
    }
}

// ---------------------------------------------------------------------------
// Decoder: comm masked-mean + tanh([h|comm]@Wc+bc) @ Wd + bd.
// grid 1024, block 512 (8 waves). Block = 8 batch rows x 32 agents.
// H (LDS): row index = agent*8 + r, 136-half stride; cols 0..63 h, 64..127 comm.
// Wave w owns agents 4w..4w+3. m-tiles use duplicated rows (lm>=8 -> lm-8),
// stores predicated to valid rows. (512,2): LDS caps at 2 blocks/CU anyway.
// ---------------------------------------------------------------------------
extern "C" __global__ __launch_bounds__(512, 2)
void dec_kernel(const _Float16* __restrict__ hws,
                const int* __restrict__ cmask,
                const float* __restrict__ bc,
                const float* __restrict__ bd,
                const _Float16* __restrict__ Wcp,
                const _Float16* __restrict__ Wdp,
                float* __restrict__ out)
{
    extern __shared__ char smem[];
    _Float16* H  = (_Float16*)smem;                  // 256 x 136
    float*    Mn = (float*)(smem + 256 * 136 * 2);   // 32 x 32
    int*      cnt = (int*)(Mn + 1024);               // 32

    const int t  = threadIdx.x;
    const int b0 = blockIdx.x * 8;

    {   // stage h tile: 8 rows x 32 agents x 64 = 2048 uint4, fully coalesced
        const uint4* src = (const uint4*)(hws + (size_t)b0 * NA * HXX);
        #pragma unroll
        for (int it = 0; it < 4; ++it) {
            int idx = it * 512 + t;
            int r = idx >> 8, rem = idx & 255, ai = rem >> 3, c8 = rem & 7;
            *(uint4*)&H[(ai * 8 + r) * 136 + c8 * 8] = src[idx];
        }
    }
    if (t < NA) {
        int c = 0;
        for (int j = 0; j < NA; ++j) c += (j != t && cmask[t * NA + j]) ? 1 : 0;
        cnt[t] = c;
    }
    __syncthreads();

    // normalized mask — grid-stride: 512 threads cover all 1024 entries
    for (int e = t; e < NA * NA; e += 512) {
        int i = e >> 5, j = e & 31;
        float v = 0.f;
        if (j != i && cmask[i * NA + j]) {
            int c = cnt[i]; v = 1.0f / (float)(c > 1 ? c : 1);
        }
        Mn[e] = v;
    }
    __syncthreads();

    {   // comm: wave w -> row r=w; lane cw handles one channel, all agents
        const int r = t >> 6, cw = t & 63;
        float hj[NA];
        #pragma unroll
        for (int j = 0; j < NA; ++j) hj[j] = (float)H[(j * 8 + r) * 136 + cw];
        for (int i = 0; i < NA; ++i) {
            float acc = 0.f;
            #pragma unroll
            for (int j = 0; j < NA; ++j) acc += Mn[i * 32 + j] * hj[j];
            H[(i * 8 + r) * 136 + 64 + cw] = (_Float16)acc;
        }
    }
    __syncthreads();

    const int w = t >> 6, l = t & 63, lm = l & 15, lq = l >> 4;
    const int rdup = lm & 7;   // rows duplicated for lm>=8

    // ---- Wc GEMM: per wave 4 agents x 4 n-tiles x K=128
    floatx4 acc[4][4];
    #pragma unroll
    for (int g = 0; g < 4; ++g)
        #pragma unroll
        for (int nt = 0; nt < 4; ++nt) acc[g][nt] = (floatx4){0.f, 0.f, 0.f, 0.f};

    for (int s = 0; s < 4; ++s) {
        #pragma unroll
        for (int g = 0; g < 4; ++g) {
            int ag = w * 4 + g;
            half8 af = *(const half8*)&H[(ag * 8 + rdup) * 136 + s * 32 + lq * 8];
            #pragma unroll
            for (int nt = 0; nt < 4; ++nt) {
                half8 bf = *(const half8*)&Wcp[(((ag * 4 + nt) * 4 + s) * 512) + l * 8];
                acc[g][nt] = MFMA16(af, bf, acc[g][nt]);
            }
        }
    }

    // tanh -> h2 (f16) into own agents' rows, cols 0..63 (valid rows only)
    #pragma unroll
    for (int g = 0; g < 4; ++g) {
        int ag = w * 4 + g;
        #pragma unroll
        for (int nt = 0; nt < 4; ++nt) {
            float bcv = bc[ag * HXX + nt * 16 + lm];
            if (lq < 2) {
                #pragma unroll
                for (int v = 0; v < 4; ++v) {
                    int m = lq * 4 + v;
                    float x = fast_tanh(acc[g][nt][v] + bcv);
                    H[(ag * 8 + m) * 136 + nt * 16 + lm] = (_Float16)x;
                }
            }
        }
    }
    // own-wave rows only -> no barrier (wave-internal LDS RAW)

    // ---- Wd GEMM: K=64, N=16
    floatx4 acc3[4];
    #pragma unroll
    for (int g = 0; g < 4; ++g) acc3[g] = (floatx4){0.f, 0.f, 0.f, 0.f};
    for (int s = 0; s < 2; ++s) {
        #pragma unroll
        for (int g = 0; g < 4; ++g) {
            int ag = w * 4 + g;
            half8 af = *(const half8*)&H[(ag * 8 + rdup) * 136 + s * 32 + lq * 8];
            half8 bf = *(const half8*)&Wdp[((ag * 2 + s) * 512) + l * 8];
            acc3[g] = MFMA16(af, bf, acc3[g]);
        }
    }

    #pragma unroll
    for (int g = 0; g < 4; ++g) {
        int ag = w * 4 + g;
        float bdv = bd[ag * NACT + lm];
        if (lq < 2) {
            #pragma unroll
            for (int v = 0; v < 4; ++v) {
                int m = lq * 4 + v;
                out[((size_t)(b0 + m) * NA + ag) * NACT + lm] = acc3[g][v] + bdv;
            }
        }
    }
}

// ---------------------------------------------------------------------------
extern "C" void kernel_launch(void* const* d_in, const int* in_sizes, int n_in,
                              void* d_out, int out_size, void* d_ws, size_t ws_size,
                              hipStream_t stream)
{
    const float* obs = (const float*)d_in[0];
    const float* W1  = (const float*)d_in[1];
    const float* b1  = (const float*)d_in[2];
    const float* W2  = (const float*)d_in[3];
    const float* b2  = (const float*)d_in[4];
    const float* Wc  = (const float*)d_in[7];
    const float* bc  = (const float*)d_in[8];
    const float* Wd  = (const float*)d_in[9];
    const float* bd  = (const float*)d_in[10];
    const int*   cm  = (const int*)d_in[11];

    float*    outp = (float*)d_out;
    _Float16* ws   = (_Float16*)d_ws;

    _Float16* hws = ws + HWS_OFF;
    _Float16* W1p = ws + W1P_OFF;
    _Float16* W2p = ws + W2P_OFF;
    _Float16* Wcp = ws + WCP_OFF;
    _Float16* Wdp = ws + WDP_OFF;

    hipLaunchKernelGGL(pack_kernel, dim3((PACK_TOTAL + 255) / 256), dim3(256), 0, stream,
                       W1, W2, Wc, Wd, ws);

    hipLaunchKernelGGL(enc_kernel, dim3(NB / 64, NA), dim3(256), 0, stream,
                       obs, b1, b2, W1p, W2p, hws);

    (void)hipFuncSetAttribute((const void*)dec_kernel,
                              hipFuncAttributeMaxDynamicSharedMemorySize, DEC_LDS);
    hipLaunchKernelGGL(dec_kernel, dim3(NB / 8), dim3(512), DEC_LDS, stream,
                       hws, cm, bc, bd, Wcp, Wdp, outp);
}

// Round 8
// 298.897 us; speedup vs baseline: 1.1903x; 1.1547x over previous
//
#include <hip/hip_runtime.h>

// QNet forward, MI355X. Round 8.
// enc: 128-row blocks, 2 m-tiles/wave (2 MFMA per B-frag load), coalesced
//      staging + transpose epilogue.
// dec: 16-row blocks, full m-tiles (no dup), comm computed into A-fragment
//      registers (linearity of fragments), h2 in C-layout regs across nt loop.
//      Normalized mask precomputed in ws (s_load).
// B=8192, A=32, NOBS=128, NH1=128, HX=64, NACT=16. fp32 in/out.

#define NB   8192
#define NA   32
#define NOBS 128
#define NH1  128
#define HXX  64
#define NACT 16

typedef _Float16 half8 __attribute__((ext_vector_type(8)));
typedef _Float16 half4 __attribute__((ext_vector_type(4)));
typedef float    floatx4 __attribute__((ext_vector_type(4)));

#define MFMA16(af, bf, c) __builtin_amdgcn_mfma_f32_16x16x32_f16((af), (bf), (c), 0, 0, 0)

// ws offsets in halfs
#define HWS_OFF 0
#define W1P_OFF (NB * NA * HXX)                    // 16,777,216
#define W1P_CNT (NA * 8 * 4 * 512)                 // 524,288
#define W2P_OFF (W1P_OFF + W1P_CNT)
#define W2P_CNT (NA * 4 * 4 * 512)                 // 262,144
#define WCP_OFF (W2P_OFF + W2P_CNT)
#define WCP_CNT (NA * 4 * 4 * 512)                 // 262,144
#define WDP_OFF (WCP_OFF + WCP_CNT)
#define WDP_CNT (NA * 1 * 2 * 512)                 // 32,768
#define MN_OFF  (WDP_OFF + WDP_CNT)                // 17,858,560 (f32 x 1024)
#define PACK_TOTAL (W1P_CNT + W2P_CNT + WCP_CNT + WDP_CNT)   // 1,081,344

#define HSTR 2056                                  // dec row slab (2048+8 pad)
#define DEC_LDS (16 * HSTR * 2)                    // 65,792 B

__device__ __forceinline__ float fast_tanh(float x) {
    x = fminf(fmaxf(x, -10.f), 10.f);
    float e2 = __expf(2.f * x);
    return (e2 - 1.f) / (e2 + 1.f);
}

// ---------------------------------------------------------------------------
// Pack: fp32 weights -> f16 MFMA B-fragments; plus normalized comm mask (f32).
// frag(a,nt,s)[l*8+j] = W[a][s*32+(l>>4)*8+j][nt*16+(l&15)]
// ---------------------------------------------------------------------------
extern "C" __global__ void pack_kernel(const float* __restrict__ W1,
                                       const float* __restrict__ W2,
                                       const float* __restrict__ Wc,
                                       const float* __restrict__ Wd,
                                       const int*   __restrict__ cmask,
                                       _Float16* __restrict__ ws)
{
    int e = blockIdx.x * 256 + threadIdx.x;
    if (e >= PACK_TOTAL + NA * NA) return;
    if (e >= PACK_TOTAL) {                       // normalized mask -> f32
        int r = e - PACK_TOTAL, i = r >> 5, j = r & 31;
        int c = 0;
        for (int jj = 0; jj < NA; ++jj) c += (jj != i && cmask[i * NA + jj]) ? 1 : 0;
        float v = 0.f;
        if (j != i && cmask[i * NA + j]) v = 1.0f / (float)(c > 1 ? c : 1);
        ((float*)(ws + MN_OFF))[r] = v;
        return;
    }
    const float* src; _Float16* dst; int K, N, NT, NS, r;
    if (e < W1P_CNT) {
        src = W1; dst = ws + W1P_OFF; K = 128; N = 128; NT = 8; NS = 4; r = e;
    } else if (e < W1P_CNT + W2P_CNT) {
        src = W2; dst = ws + W2P_OFF; K = 128; N = 64; NT = 4; NS = 4; r = e - W1P_CNT;
    } else if (e < W1P_CNT + W2P_CNT + WCP_CNT) {
        src = Wc; dst = ws + WCP_OFF; K = 128; N = 64; NT = 4; NS = 4; r = e - W1P_CNT - W2P_CNT;
    } else {
        src = Wd; dst = ws + WDP_OFF; K = 64; N = 16; NT = 1; NS = 2; r = e - W1P_CNT - W2P_CNT - WCP_CNT;
    }
    int j = r & 7, l = (r >> 3) & 63;
    int rest = r >> 9;
    int s  = rest % NS; rest /= NS;
    int nt = rest % NT; rest /= NT;
    int a  = rest;
    int k = s * 32 + (l >> 4) * 8 + j;
    int n = nt * 16 + (l & 15);
    dst[r] = (_Float16)src[((size_t)a * K + k) * N + n];
}

// ---------------------------------------------------------------------------
// Encoder: h = relu(relu(obs@W1+b1)@W2+b2) -> ws (f16, [b][a][c])
// grid (64, 32), block 256 (4 waves). 128 rows/block; wave w owns rows
// 32w..32w+31 (2 m-tiles -> 2 MFMA per B-frag load).
// ---------------------------------------------------------------------------
extern "C" __global__ __launch_bounds__(256)
void enc_kernel(const float* __restrict__ obs,
                const float* __restrict__ b1,
                const float* __restrict__ b2,
                const _Float16* __restrict__ W1p,
                const _Float16* __restrict__ W2p,
                _Float16* __restrict__ hws)
{
    __shared__ _Float16 A[128 * 136];   // 34,816 B

    const int t  = threadIdx.x;
    const int a  = blockIdx.y;
    const int b0 = blockIdx.x * 128;

    {   // stage obs fp32 -> f16: 8 lanes/row, 128B contiguous chunks
        const int j = t & 7;
        #pragma unroll
        for (int p = 0; p < 4; ++p) {
            const int row = (t >> 3) + 32 * p;
            const float4* src = (const float4*)(obs + ((size_t)(b0 + row) * NA + a) * NOBS);
            _Float16* dst = A + row * 136;
            #pragma unroll
            for (int q = 0; q < 4; ++q) {
                float4 g = src[j + 8 * q];
                half4 hv; hv[0] = (_Float16)g.x; hv[1] = (_Float16)g.y;
                hv[2] = (_Float16)g.z; hv[3] = (_Float16)g.w;
                *(half4*)&dst[(j + 8 * q) * 4] = hv;
            }
        }
    }
    const int w = t >> 6, l = t & 63, lm = l & 15, lq = l >> 4;

    float b1v[8], b2v[4];
    #pragma unroll
    for (int nt = 0; nt < 8; ++nt) b1v[nt] = b1[a * NH1 + nt * 16 + lm];
    #pragma unroll
    for (int nt = 0; nt < 4; ++nt) b2v[nt] = b2[a * HXX + nt * 16 + lm];

    __syncthreads();
    // Each wave touches only rows 32w..32w+31 from here: no more barriers.

    // ---- GEMM1: x = obs @ W1  (2 m-tiles x 8 n-tiles, K=128)
    floatx4 acc[2][8];
    #pragma unroll
    for (int mt = 0; mt < 2; ++mt)
        #pragma unroll
        for (int nt = 0; nt < 8; ++nt) acc[mt][nt] = (floatx4){0.f, 0.f, 0.f, 0.f};
    for (int s = 0; s < 4; ++s) {
        half8 af[2];
        #pragma unroll
        for (int mt = 0; mt < 2; ++mt)
            af[mt] = *(const half8*)&A[(w * 32 + mt * 16 + lm) * 136 + s * 32 + lq * 8];
        #pragma unroll
        for (int nt = 0; nt < 8; ++nt) {
            half8 bf = *(const half8*)&W1p[(((a * 8 + nt) * 4 + s) * 512) + l * 8];
            acc[0][nt] = MFMA16(af[0], bf, acc[0][nt]);
            acc[1][nt] = MFMA16(af[1], bf, acc[1][nt]);
        }
    }
    #pragma unroll
    for (int mt = 0; mt < 2; ++mt)
        #pragma unroll
        for (int nt = 0; nt < 8; ++nt)
            #pragma unroll
            for (int v = 0; v < 4; ++v) {
                float x = fmaxf(acc[mt][nt][v] + b1v[nt], 0.f);
                A[(w * 32 + mt * 16 + lq * 4 + v) * 136 + nt * 16 + lm] = (_Float16)x;
            }

    // ---- GEMM2: h = X @ W2  (2 m-tiles x 4 n-tiles)
    floatx4 acc2[2][4];
    #pragma unroll
    for (int mt = 0; mt < 2; ++mt)
        #pragma unroll
        for (int nt = 0; nt < 4; ++nt) acc2[mt][nt] = (floatx4){0.f, 0.f, 0.f, 0.f};
    for (int s = 0; s < 4; ++s) {
        half8 af[2];
        #pragma unroll
        for (int mt = 0; mt < 2; ++mt)
            af[mt] = *(const half8*)&A[(w * 32 + mt * 16 + lm) * 136 + s * 32 + lq * 8];
        #pragma unroll
        for (int nt = 0; nt < 4; ++nt) {
            half8 bf = *(const half8*)&W2p[(((a * 4 + nt) * 4 + s) * 512) + l * 8];
            acc2[0][nt] = MFMA16(af[0], bf, acc2[0][nt]);
            acc2[1][nt] = MFMA16(af[1], bf, acc2[1][nt]);
        }
    }
    #pragma unroll
    for (int mt = 0; mt < 2; ++mt)
        #pragma unroll
        for (int nt = 0; nt < 4; ++nt)
            #pragma unroll
            for (int v = 0; v < 4; ++v) {
                float x = fmaxf(acc2[mt][nt][v] + b2v[nt], 0.f);
                A[(w * 32 + mt * 16 + lq * 4 + v) * 136 + nt * 16 + lm] = (_Float16)x;
            }
    {   // transpose epilogue: coalesced b128 h stores
        const int rr = l >> 2, cc = l & 3;
        #pragma unroll
        for (int mt = 0; mt < 2; ++mt)
            #pragma unroll
            for (int hh = 0; hh < 2; ++hh) {
                const int chunk = cc + 4 * hh;
                const int row = w * 32 + mt * 16 + rr;
                half8 hv = *(const half8*)&A[row * 136 + chunk * 8];
                *(half8*)&hws[((size_t)(b0 + row) * NA + a) * HXX + chunk * 8] = hv;
            }
    }
}

// ---------------------------------------------------------------------------
// Decoder: comm masked-mean + tanh([h|comm]@Wc+bc) @ Wd + bd.
// grid 512, block 512 (8 waves). Block = 16 batch rows x 32 agents.
// H (LDS): [row][agent*64+c], row slab HSTR halfs. Wave w owns agents
// 4w..4w+3, full 16-row m-tiles. comm lives in A-frag registers (hacc):
// frag_comm(i,s) = sum_j Mn[i][j] * frag_h(j, s-2)  (fragment linearity).
// h2 in C-layout regs across nt loop; single LDS write for Wd GEMM.
// ---------------------------------------------------------------------------
extern "C" __global__ __launch_bounds__(512)
void dec_kernel(const _Float16* __restrict__ hws,
                const float* __restrict__ MnG,
                const float* __restrict__ bc,
                const float* __restrict__ bd,
                const _Float16* __restrict__ Wcp,
                const _Float16* __restrict__ Wdp,
                float* __restrict__ out)
{
    extern __shared__ char smem[];
    _Float16* H = (_Float16*)smem;   // 16 x HSTR

    const int t  = threadIdx.x;
    const int b0 = blockIdx.x * 16;

    {   // stage h tile: 16 rows x 32 ag x 64 ch = 4096 uint4, coalesced
        const uint4* src = (const uint4*)(hws + (size_t)b0 * NA * HXX);
        #pragma unroll
        for (int it = 0; it < 8; ++it) {
            int idx = it * 512 + t;
            int row = idx >> 8, rem = idx & 255;
            *(uint4*)&H[row * HSTR + rem * 8] = src[idx];
        }
    }
    __syncthreads();

    const int w = t >> 6, l = t & 63, lm = l & 15, lq = l >> 4;

    // ---- comm into A-frag registers (reads ALL rows; barrier after)
    half8 hacc[4][2];
    #pragma unroll
    for (int g = 0; g < 4; ++g)
        #pragma unroll
        for (int sb = 0; sb < 2; ++sb)
            #pragma unroll
            for (int q = 0; q < 8; ++q) hacc[g][sb][q] = (_Float16)0.f;

    #pragma unroll 4
    for (int j = 0; j < NA; ++j) {
        half8 v0 = *(const half8*)&H[lm * HSTR + j * 64 + lq * 8];
        half8 v1 = *(const half8*)&H[lm * HSTR + j * 64 + 32 + lq * 8];
        #pragma unroll
        for (int g = 0; g < 4; ++g) {
            int ag = __builtin_amdgcn_readfirstlane(w * 4 + g);
            _Float16 mh = (_Float16)MnG[ag * NA + j];   // s_load, wave-uniform
            hacc[g][0] += v0 * mh;
            hacc[g][1] += v1 * mh;
        }
    }
    __syncthreads();   // all comm reads done before any h2 overwrite
    // From here each wave touches only its own agents' columns.

    // ---- Wc GEMM per n-tile; h2 kept in C-layout regs
    half4 h2r[4][4];
    #pragma unroll
    for (int nt = 0; nt < 4; ++nt) {
        floatx4 acc[4];
        #pragma unroll
        for (int g = 0; g < 4; ++g) acc[g] = (floatx4){0.f, 0.f, 0.f, 0.f};
        #pragma unroll
        for (int s = 0; s < 4; ++s) {
            #pragma unroll
            for (int g = 0; g < 4; ++g) {
                int ag = w * 4 + g;
                half8 af = (s < 2)
                    ? *(const half8*)&H[lm * HSTR + ag * 64 + s * 32 + lq * 8]
                    : hacc[g][s - 2];
                half8 bf = *(const half8*)&Wcp[(((ag * 4 + nt) * 4 + s) * 512) + l * 8];
                acc[g] = MFMA16(af, bf, acc[g]);
            }
        }
        #pragma unroll
        for (int g = 0; g < 4; ++g) {
            int ag = w * 4 + g;
            float bcv = bc[ag * HXX + nt * 16 + lm];
            #pragma unroll
            for (int v = 0; v < 4; ++v)
                h2r[g][nt][v] = (_Float16)fast_tanh(acc[g][v] + bcv);
        }
    }

    // write h2 over own agents' h (all Wc reads of those columns are done)
    #pragma unroll
    for (int g = 0; g < 4; ++g) {
        int ag = w * 4 + g;
        #pragma unroll
        for (int nt = 0; nt < 4; ++nt)
            #pragma unroll
            for (int v = 0; v < 4; ++v)
                H[(lq * 4 + v) * HSTR + ag * 64 + nt * 16 + lm] = h2r[g][nt][v];
    }
    // wave-internal LDS RAW -> compiler lgkmcnt; no cross-wave access

    // ---- Wd GEMM: K=64, N=16
    floatx4 acc3[4];
    #pragma unroll
    for (int g = 0; g < 4; ++g) acc3[g] = (floatx4){0.f, 0.f, 0.f, 0.f};
    #pragma unroll
    for (int s = 0; s < 2; ++s) {
        #pragma unroll
        for (int g = 0; g < 4; ++g) {
            int ag = w * 4 + g;
            half8 af = *(const half8*)&H[lm * HSTR + ag * 64 + s * 32 + lq * 8];
            half8 bf = *(const half8*)&Wdp[((ag * 2 + s) * 512) + l * 8];
            acc3[g] = MFMA16(af, bf, acc3[g]);
        }
    }

    #pragma unroll
    for (int g = 0; g < 4; ++g) {
        int ag = w * 4 + g;
        float bdv = bd[ag * NACT + lm];
        #pragma unroll
        for (int v = 0; v < 4; ++v) {
            int row = lq * 4 + v;
            out[((size_t)(b0 + row) * NA + ag) * NACT + lm] = acc3[g][v] + bdv;
        }
    }
}

// ---------------------------------------------------------------------------
extern "C" void kernel_launch(void* const* d_in, const int* in_sizes, int n_in,
                              void* d_out, int out_size, void* d_ws, size_t ws_size,
                              hipStream_t stream)
{
    const float* obs = (const float*)d_in[0];
    const float* W1  = (const float*)d_in[1];
    const float* b1  = (const float*)d_in[2];
    const float* W2  = (const float*)d_in[3];
    const float* b2  = (const float*)d_in[4];
    const float* Wc  = (const float*)d_in[7];
    const float* bc  = (const float*)d_in[8];
    const float* Wd  = (const float*)d_in[9];
    const float* bd  = (const float*)d_in[10];
    const int*   cm  = (const int*)d_in[11];

    float*    outp = (float*)d_out;
    _Float16* ws   = (_Float16*)d_ws;

    _Float16* hws = ws + HWS_OFF;
    _Float16* W1p = ws + W1P_OFF;
    _Float16* W2p = ws + W2P_OFF;
    _Float16* Wcp = ws + WCP_OFF;
    _Float16* Wdp = ws + WDP_OFF;
    const float* MnG = (const float*)(ws + MN_OFF);

    hipLaunchKernelGGL(pack_kernel, dim3((PACK_TOTAL + NA * NA + 255) / 256),
                       dim3(256), 0, stream, W1, W2, Wc, Wd, cm, ws);

    hipLaunchKernelGGL(enc_kernel, dim3(NB / 128, NA), dim3(256), 0, stream,
                       obs, b1, b2, W1p, W2p, hws);

    (void)hipFuncSetAttribute((const void*)dec_kernel,
                              hipFuncAttributeMaxDynamicSharedMemorySize, DEC_LDS);
    hipLaunchKernelGGL(dec_kernel, dim3(NB / 16), dim3(512), DEC_LDS, stream,
                       hws, MnG, bc, bd, Wcp, Wdp, outp);
}